// Round 4
// baseline (91.491 us; speedup 1.0000x reference)
//
#include <hip/hip_runtime.h>
#include <hip/hip_bf16.h>

// Problem constants (B=4, L=4096, C=512, H=16, Dh=32, K=13)
#define BATCH   4
#define LSEQ    4096
#define CCH     512
#define HNUM    16
#define DH      32
#define KSZ     13
#define NHALF   6           // K/2
#define M_TOT   16384       // B*L
#define N_QKV   1536        // 3*C
#define KDIM    512         // C
#define BK      64          // GEMM K-step (128B rows -> XOR-swizzle domain of 8 chunks)

typedef __attribute__((ext_vector_type(8))) short  short8;
typedef __attribute__((ext_vector_type(4))) short  short4_t;
typedef __attribute__((ext_vector_type(4))) float  float4_t;

__device__ __forceinline__ unsigned short f32_to_bf16(float f) {
    union { float f; unsigned int u; } un; un.f = f;
    unsigned int u = un.u;
    u += 0x7FFFu + ((u >> 16) & 1u);   // RNE (inputs are finite)
    return (unsigned short)(u >> 16);
}
__device__ __forceinline__ float bf16_to_f32(unsigned short h) {
    union { unsigned int u; float f; } un; un.u = ((unsigned int)h) << 16;
    return un.f;
}

// async global(16B/lane) -> LDS; lds base must be wave-uniform, HW adds lane*16
__device__ __forceinline__ void gload_lds16(const unsigned short* g, unsigned short* l) {
    __builtin_amdgcn_global_load_lds(
        (const __attribute__((address_space(1))) unsigned int*)g,
        (__attribute__((address_space(3))) unsigned int*)l,
        16, 0, 0);
}

// ---------------------------------------------------------------- cvt f32->bf16
__global__ void cvt_f32_bf16_v4(const float4_t* __restrict__ in,
                                short4_t* __restrict__ out, int n4) {
    int i = blockIdx.x * blockDim.x + threadIdx.x;
    int stride = gridDim.x * blockDim.x;
    for (; i < n4; i += stride) {
        float4_t v = in[i];
        short4_t h;
        h.x = (short)f32_to_bf16(v.x);
        h.y = (short)f32_to_bf16(v.y);
        h.z = (short)f32_to_bf16(v.z);
        h.w = (short)f32_to_bf16(v.w);
        out[i] = h;
    }
}

// ---------------------------------------------------------------- GEMM 1: QKV
// Xb (bf16, 16384x512) @ W^T (W bf16 1536x512) + bias -> qkv bf16 (3,B,H,L,Dh)
// 256x256 tile, BK=64, 8 waves (2M x 4N), per-wave 128x64 output.
// Full-tile double-buffer + counted vmcnt(8) (never 0 in loop) + raw s_barrier
// + per-phase setprio around 16-MFMA clusters (T3+T4+T5).
// LDS 128 KB dynamic: A[2][256][64] | B[2][256][64], XOR chunk swizzle
// (slot c holds global chunk c ^ (row&7); reads apply same involution).
__global__ __launch_bounds__(512, 2) void gemm_qkv(
    const unsigned short* __restrict__ Xb,
    const unsigned short* __restrict__ W,
    const float* __restrict__ bias,
    unsigned short* __restrict__ qkvout)
{
    extern __shared__ __align__(16) unsigned short lds[];   // 131072 B
    // A buf b: lds[b*16384 + row*64 + e]; B buf b: lds[32768 + b*16384 + row*64 + e]
    const int tid  = threadIdx.x;
    const int wv   = tid >> 6, ln = tid & 63;

    // bijective XCD swizzle (384 % 8 == 0), column-major tile decode
    const int wg   = blockIdx.x;
    const int swz  = (wg & 7) * 48 + (wg >> 3);
    const int m0   = (swz & 63) * 256;      // 64 M-tiles
    const int n0   = (swz >> 6) * 256;      // 6 N-tiles

    const int wm   = (wv >> 2) * 128;       // 2 M-halves of waves
    const int wn   = (wv & 3) * 64;         // 4 N-quarters
    const int lr   = ln & 15;               // fragment row/col
    const int lg   = ln >> 4;               // k-group (0..3)
    const int rgrp = ln >> 3;               // staging: row within 8-row chunk
    const int csw  = ((ln & 7) ^ rgrp) * 8; // staging: swizzled source chunk (elems)

    float4_t acc[8][4];
    #pragma unroll
    for (int m = 0; m < 8; ++m)
        #pragma unroll
        for (int n = 0; n < 4; ++n)
            acc[m][n] = (float4_t){0.f, 0.f, 0.f, 0.f};

    // stage full K-tile `t` (A 32KB + B 32KB) into buffer `buf`
    // wave wv owns rows [wv*32, wv*32+32) of both A and B: 4+4 gload_lds of 1KB
    #define STAGE(t_, buf_) do {                                              \
        const int k0_ = (t_) * BK;                                            \
        _Pragma("unroll")                                                     \
        for (int c4 = 0; c4 < 4; ++c4) {                                      \
            int r_ = wv * 32 + c4 * 8;                                        \
            gload_lds16(Xb + (size_t)(m0 + r_ + rgrp) * KDIM + k0_ + csw,     \
                        &lds[(buf_) * 16384 + r_ * 64]);                      \
            gload_lds16(W  + (size_t)(n0 + r_ + rgrp) * KDIM + k0_ + csw,     \
                        &lds[32768 + (buf_) * 16384 + r_ * 64]);              \
        }                                                                     \
    } while (0)

    STAGE(0, 0);   // prologue: tile 0 -> buf 0 (8 loads outstanding)

    #pragma unroll 2
    for (int t = 0; t < 8; ++t) {
        const int buf = t & 1;
        if (t < 7) {
            STAGE(t + 1, buf ^ 1);                         // 8 more in flight
            asm volatile("s_waitcnt vmcnt(8)" ::: "memory");  // tile t landed
        } else {
            asm volatile("s_waitcnt vmcnt(0)" ::: "memory");  // drain last tile
        }
        __builtin_amdgcn_s_barrier();                      // publish buf to all waves

        const unsigned short* Ab = &lds[buf * 16384];
        const unsigned short* Bb = &lds[32768 + buf * 16384];

        short8 af[2][4], bf[2][2];
        #pragma unroll
        for (int qm = 0; qm < 2; ++qm) {
            // A-frags for this m-half (shared by both qn phases)
            #pragma unroll
            for (int kk = 0; kk < 2; ++kk)
                #pragma unroll
                for (int m = 0; m < 4; ++m) {
                    int row = wm + qm * 64 + m * 16 + lr;
                    int c   = (kk * 4 + lg) ^ (lr & 7);
                    af[kk][m] = *reinterpret_cast<const short8*>(&Ab[row * 64 + c * 8]);
                }
            #pragma unroll
            for (int qn = 0; qn < 2; ++qn) {
                #pragma unroll
                for (int kk = 0; kk < 2; ++kk)
                    #pragma unroll
                    for (int n = 0; n < 2; ++n) {
                        int row = wn + qn * 32 + n * 16 + lr;
                        int c   = (kk * 4 + lg) ^ (lr & 7);
                        bf[kk][n] = *reinterpret_cast<const short8*>(&Bb[row * 64 + c * 8]);
                    }
                __builtin_amdgcn_s_barrier();              // phase gate
                __builtin_amdgcn_sched_barrier(0);
                __builtin_amdgcn_s_setprio(1);
                #pragma unroll
                for (int kk = 0; kk < 2; ++kk)
                    #pragma unroll
                    for (int m = 0; m < 4; ++m)
                        #pragma unroll
                        for (int n = 0; n < 2; ++n)
                            acc[qm * 4 + m][qn * 2 + n] =
                                __builtin_amdgcn_mfma_f32_16x16x32_bf16(
                                    af[kk][m], bf[kk][n],
                                    acc[qm * 4 + m][qn * 2 + n], 0, 0, 0);
                __builtin_amdgcn_s_setprio(0);
            }
        }
    }
    #undef STAGE

    // epilogue: bias, q-scale, scatter to (3,B,H,L,Dh) bf16
    const float qscale = 0.17677669529663687f;  // Dh^-0.5
    #pragma unroll
    for (int mf = 0; mf < 8; ++mf) {
        #pragma unroll
        for (int nf = 0; nf < 4; ++nf) {
            int gn    = n0 + wn + nf * 16 + lr;
            int which = gn >> 9;            // 0=q 1=k 2=v
            int hh    = (gn >> 5) & 15;
            int dd    = gn & 31;
            float bsv = bias[gn];
            #pragma unroll
            for (int r = 0; r < 4; ++r) {
                int gm = m0 + wm + mf * 16 + lg * 4 + r;
                float v = acc[mf][nf][r] + bsv;
                if (which == 0) v *= qscale;
                int b_ = gm >> 12, l = gm & 4095;
                size_t off = (((size_t)which * BATCH + b_) * HNUM + hh) *
                                 ((size_t)LSEQ * DH) + (size_t)l * DH + dd;
                qkvout[off] = f32_to_bf16(v);
            }
        }
    }
}

// ---------------------------------------------------------------- attention
// one block = (b, h, 256 consecutive l). K/V window staged in LDS as
// [cq][row][8] planes (16B row stride): lane-consecutive rows hit all 32 banks.
__global__ __launch_bounds__(256) void natten_fwd(
    const unsigned short* __restrict__ qkv,  // (3,B,H,L,Dh) bf16
    const float* __restrict__ rpb,           // (16,25) f32
    unsigned short* __restrict__ ctx)        // (B,L,C) bf16
{
    __shared__ __align__(16) unsigned short ks[4 * 268 * 8];
    __shared__ __align__(16) unsigned short vs[4 * 268 * 8];
    __shared__ float rpb_s[2 * KSZ - 1];

    const int t    = threadIdx.x;
    const int lblk = blockIdx.x & 15;       // L/256 = 16 chunks
    const int bh   = blockIdx.x >> 4;
    const int hh   = bh & 15, b_ = bh >> 4;
    const int l0   = lblk * 256;

    const int r0    = max(l0 - NHALF, 0);
    const int rend  = min(l0 + 256 + NHALF, LSEQ);
    const int nrows = rend - r0;            // <= 268

    const size_t plane = (size_t)LSEQ * DH;
    const size_t kbase = (((size_t)1 * BATCH + b_) * HNUM + hh) * plane;
    const size_t vbase = (((size_t)2 * BATCH + b_) * HNUM + hh) * plane;

    // per 256-thread pass: 64 rows x 4 d-chunks; wave = one d-chunk, rows consecutive
    {
        const int cq  = t >> 6;
        const int rr  = t & 63;
        #pragma unroll
        for (int base = 0; base < 320; base += 64) {
            int row = base + rr;
            if (row < nrows) {
                *reinterpret_cast<short8*>(&ks[(cq * 268 + row) * 8]) =
                    *reinterpret_cast<const short8*>(&qkv[kbase + (size_t)(r0 + row) * DH + cq * 8]);
                *reinterpret_cast<short8*>(&vs[(cq * 268 + row) * 8]) =
                    *reinterpret_cast<const short8*>(&qkv[vbase + (size_t)(r0 + row) * DH + cq * 8]);
            }
        }
    }
    if (t < 2 * KSZ - 1) rpb_s[t] = rpb[hh * (2 * KSZ - 1) + t];
    __syncthreads();

    const int l = l0 + t;
    float q[DH];
    const size_t qoff = (((size_t)0 * BATCH + b_) * HNUM + hh) * plane + (size_t)l * DH;
    #pragma unroll
    for (int cq = 0; cq < 4; ++cq) {
        short8 qv = *reinterpret_cast<const short8*>(&qkv[qoff + cq * 8]);
        #pragma unroll
        for (int e = 0; e < 8; ++e) q[cq * 8 + e] = bf16_to_f32((unsigned short)qv[e]);
    }

    const int start = min(max(l - NHALF, 0), LSEQ - KSZ);
    float logit[KSZ];
    #pragma unroll
    for (int j = 0; j < KSZ; ++j) {
        int kr = start + j - r0;
        float s = 0.f;
        #pragma unroll
        for (int cq = 0; cq < 4; ++cq) {
            short8 kv = *reinterpret_cast<const short8*>(&ks[(cq * 268 + kr) * 8]);
            #pragma unroll
            for (int e = 0; e < 8; ++e)
                s += q[cq * 8 + e] * bf16_to_f32((unsigned short)kv[e]);
        }
        logit[j] = s + rpb_s[start + j - l + (KSZ - 1)];
    }
    float mx = logit[0];
    #pragma unroll
    for (int j = 1; j < KSZ; ++j) mx = fmaxf(mx, logit[j]);
    float p[KSZ], sum = 0.f;
    #pragma unroll
    for (int j = 0; j < KSZ; ++j) { p[j] = __expf(logit[j] - mx); sum += p[j]; }
    const float inv = 1.f / sum;

    float o[DH];
    #pragma unroll
    for (int d = 0; d < DH; ++d) o[d] = 0.f;
    #pragma unroll
    for (int j = 0; j < KSZ; ++j) {
        int kr = start + j - r0;
        float pj = p[j] * inv;
        #pragma unroll
        for (int cq = 0; cq < 4; ++cq) {
            short8 vv = *reinterpret_cast<const short8*>(&vs[(cq * 268 + kr) * 8]);
            #pragma unroll
            for (int e = 0; e < 8; ++e)
                o[cq * 8 + e] += pj * bf16_to_f32((unsigned short)vv[e]);
        }
    }
    const size_t obase = ((size_t)(b_ * LSEQ + l)) * CCH + hh * DH;
    #pragma unroll
    for (int cq = 0; cq < 4; ++cq) {
        short8 ov;
        #pragma unroll
        for (int e = 0; e < 8; ++e) ov[e] = (short)f32_to_bf16(o[cq * 8 + e]);
        *reinterpret_cast<short8*>(&ctx[obase + cq * 8]) = ov;
    }
}

// ---------------------------------------------------------------- GEMM 2: proj
// ctx (bf16, 16384x512) @ W^T (W bf16 512x512) + bias -> out f32 (B,L,C)
__global__ __launch_bounds__(256) void gemm_proj(
    const unsigned short* __restrict__ Xb,
    const unsigned short* __restrict__ W,
    const float* __restrict__ bias,
    float* __restrict__ out)
{
    __shared__ __align__(16) unsigned short As[128 * BK];
    __shared__ __align__(16) unsigned short Bs[128 * BK];
    const int tid  = threadIdx.x;
    const int wv   = tid >> 6, ln = tid & 63;
    const int m0   = blockIdx.x * 128;
    const int n0   = blockIdx.y * 128;
    const int wm   = (wv >> 1) * 64;
    const int wn   = (wv & 1) * 64;
    const int lr   = ln & 15;
    const int lg   = ln >> 4;
    const int rgrp = ln >> 3;
    const int csw  = ((ln & 7) ^ rgrp) * 8;

    float4_t acc[4][4];
    #pragma unroll
    for (int m = 0; m < 4; ++m)
        #pragma unroll
        for (int n = 0; n < 4; ++n)
            acc[m][n] = (float4_t){0.f, 0.f, 0.f, 0.f};

    for (int k0 = 0; k0 < KDIM; k0 += BK) {
        #pragma unroll
        for (int it = 0; it < 4; ++it) {
            int ch  = it * 4 + wv;
            int row = ch * 8 + rgrp;
            gload_lds16(Xb + (size_t)(m0 + row) * KDIM + k0 + csw,
                        &As[ch * 8 * BK]);
            gload_lds16(W  + (size_t)(n0 + row) * KDIM + k0 + csw,
                        &Bs[ch * 8 * BK]);
        }
        __syncthreads();
        short8 af[2][4], bfr[2][4];
        #pragma unroll
        for (int kk = 0; kk < 2; ++kk) {
            #pragma unroll
            for (int m = 0; m < 4; ++m) {
                int row = wm + m * 16 + lr;
                int c   = (kk * 4 + lg) ^ (row & 7);
                af[kk][m] = *reinterpret_cast<const short8*>(&As[row * BK + c * 8]);
            }
            #pragma unroll
            for (int n = 0; n < 4; ++n) {
                int row = wn + n * 16 + lr;
                int c   = (kk * 4 + lg) ^ (row & 7);
                bfr[kk][n] = *reinterpret_cast<const short8*>(&Bs[row * BK + c * 8]);
            }
        }
        #pragma unroll
        for (int kk = 0; kk < 2; ++kk)
            #pragma unroll
            for (int m = 0; m < 4; ++m)
                #pragma unroll
                for (int n = 0; n < 4; ++n)
                    acc[m][n] = __builtin_amdgcn_mfma_f32_16x16x32_bf16(
                        af[kk][m], bfr[kk][n], acc[m][n], 0, 0, 0);
        __syncthreads();
    }

    #pragma unroll
    for (int m = 0; m < 4; ++m) {
        #pragma unroll
        for (int n = 0; n < 4; ++n) {
            int gn = n0 + wn + n * 16 + lr;
            float bsv = bias[gn];
            #pragma unroll
            for (int r = 0; r < 4; ++r) {
                int gm = m0 + wm + m * 16 + lg * 4 + r;
                out[(size_t)gm * CCH + gn] = acc[m][n][r] + bsv;
            }
        }
    }
}

// ---------------------------------------------------------------- launch
extern "C" void kernel_launch(void* const* d_in, const int* in_sizes, int n_in,
                              void* d_out, int out_size, void* d_ws, size_t ws_size,
                              hipStream_t stream) {
    const float* x      = (const float*)d_in[0];
    const float* qkv_w  = (const float*)d_in[1];
    const float* qkv_b  = (const float*)d_in[2];
    const float* rpb    = (const float*)d_in[3];
    const float* proj_w = (const float*)d_in[4];
    const float* proj_b = (const float*)d_in[5];
    float* out = (float*)d_out;
    char* ws = (char*)d_ws;

    // ws layout (bytes):
    //   qkv bf16 (3*B*H*L*Dh = 25165824 elems)   @ 0          : 50331648
    //   xb/ctx overlay (8388608 elems bf16)      @ 50331648   : 16777216
    //   qkv_w bf16 (786432 elems)                @ 67108864   :  1572864
    //   proj_w bf16 (262144 elems)               @ 68681728   :   524288
    unsigned short* qkv = (unsigned short*)(ws);
    unsigned short* xb  = (unsigned short*)(ws + 50331648);
    unsigned short* ctx = (unsigned short*)(ws + 50331648);
    unsigned short* wq  = (unsigned short*)(ws + 67108864);
    unsigned short* wp  = (unsigned short*)(ws + 68681728);

    cvt_f32_bf16_v4<<<2048, 256, 0, stream>>>((const float4_t*)x, (short4_t*)xb, M_TOT * KDIM / 4);
    cvt_f32_bf16_v4<<<768, 256, 0, stream>>>((const float4_t*)qkv_w, (short4_t*)wq, 786432 / 4);
    cvt_f32_bf16_v4<<<256, 256, 0, stream>>>((const float4_t*)proj_w, (short4_t*)wp, 262144 / 4);

    // 256x256 tiles: 64 x 6 = 384 blocks, 512 threads, 128 KB dynamic LDS
    gemm_qkv<<<384, 512, 131072, stream>>>(xb, wq, qkv_b, qkv);

    natten_fwd<<<BATCH * HNUM * (LSEQ / 256), 256, 0, stream>>>(qkv, rpb, ctx);

    dim3 g2(M_TOT / 128, CCH / 128);     // 128 x 4
    gemm_proj<<<g2, 256, 0, stream>>>(ctx, wp, proj_b, out);
}